// Round 12
// baseline (653.092 us; speedup 1.0000x reference)
//
#include <hip/hip_runtime.h>
#include <math.h>

// Problem constants
#define NN 118   // nodes
#define EE 372   // edges
#define GG 2048  // B*T
#define DD 128   // hidden
#define TT 256   // seq len
#define BB 8     // batch
#define FD 512   // 4*D

// LDS stride for bf16 matrices (rows 16B-aligned, 2-way-max bank aliasing)
#define XS 136

typedef short bf16x8 __attribute__((ext_vector_type(8)));
typedef float f32x4  __attribute__((ext_vector_type(4)));
typedef _Float16 f16x2 __attribute__((ext_vector_type(2)));

__device__ __forceinline__ float frcp_(float x) { return __builtin_amdgcn_rcpf(x); }
__device__ __forceinline__ float sig_f(float x) { return frcp_(1.0f + __expf(-x)); }
__device__ __forceinline__ float tanh_f(float x) { return 1.0f - 2.0f * frcp_(__expf(2.0f * x) + 1.0f); }
__device__ __forceinline__ float silu_f(float x) { return x * frcp_(1.0f + __expf(-x)); }
__device__ __forceinline__ float siluf_(float x) { return x / (1.0f + expf(-x)); }

// f16-pair dot with fp32 accumulate (v_dot2_f32_f16); scalar fallback.
__device__ __forceinline__ float fdot2_(unsigned int a, unsigned int b, float c) {
#if defined(__has_builtin) && __has_builtin(__builtin_amdgcn_fdot2)
    return __builtin_amdgcn_fdot2(__builtin_bit_cast(f16x2, a),
                                  __builtin_bit_cast(f16x2, b), c, false);
#else
    f16x2 x = __builtin_bit_cast(f16x2, a), y = __builtin_bit_cast(f16x2, b);
    return c + (float)x[0] * (float)y[0] + (float)x[1] * (float)y[1];
#endif
}

// Barrier draining only LDS ops (lgkmcnt), not vmcnt: global stores stay
// fire-and-forget, prefetch loads stay in flight. Safe: all cross-thread data
// flows through LDS (global->VGPR uses get compiler vmcnt waits).
__device__ __forceinline__ void bar_lds() {
    asm volatile("s_waitcnt lgkmcnt(0)\n\ts_barrier" ::: "memory");
}

__device__ __forceinline__ unsigned short f2bf(float x) {
    unsigned int u = __float_as_uint(x);
    unsigned int r = (u + 0x7fffu + ((u >> 16) & 1u)) >> 16;
    return (unsigned short)r;
}
__device__ __forceinline__ float bf2f(unsigned short b) {
    return __uint_as_float(((unsigned int)b) << 16);
}

// ---------------------------------------------------------------------------
// prep: dense normalized adjacency A -> bf16 128x128 (zero padded), fused
// LSTM biases (plain gate-major order). 1 block.
// ---------------------------------------------------------------------------
__global__ void prep_kernel(const int* __restrict__ ei,
                            const float* __restrict__ bih0, const float* __restrict__ bhh0,
                            const float* __restrict__ bih1, const float* __restrict__ bhh1,
                            float* __restrict__ bias0, float* __restrict__ bias1,
                            unsigned short* __restrict__ AbG) {
    __shared__ int sflag;
    __shared__ int ssrc[EE], sdst[EE];
    __shared__ int scount[NN];
    __shared__ float sinv[NN];
    __shared__ float Adense[NN * NN];  // 55.7 KB
    int tid = threadIdx.x;
    if (tid == 0) sflag = 0;
    __syncthreads();
    // int64-vs-int32 layout detect (values < 118 -> high words zero if int64)
    for (int i = tid; i < 2 * EE; i += blockDim.x)
        if ((i & 1) && ei[i] != 0) atomicOr(&sflag, 1);
    __syncthreads();
    bool m64 = (sflag == 0);
    for (int e = tid; e < EE; e += blockDim.x) {
        int s, d;
        if (m64) { s = ei[2 * e]; d = ei[2 * EE + 2 * e]; }
        else     { s = ei[e];     d = ei[EE + e]; }
        s = min(max(s, 0), NN - 1); d = min(max(d, 0), NN - 1);
        ssrc[e] = s; sdst[e] = d;
    }
    for (int n = tid; n < NN; n += blockDim.x) scount[n] = 0;
    for (int i = tid; i < NN * NN; i += blockDim.x) Adense[i] = 0.0f;
    __syncthreads();
    for (int e = tid; e < EE; e += blockDim.x) atomicAdd(&scount[sdst[e]], 1);
    __syncthreads();
    for (int n = tid; n < NN; n += blockDim.x) {
        float deg = 1.0f + (float)scount[n];
        sinv[n] = rsqrtf(deg);
        Adense[n * NN + n] = 1.0f / deg;   // self term h*(1/deg)
    }
    __syncthreads();
    for (int e = tid; e < EE; e += blockDim.x)
        atomicAdd(&Adense[sdst[e] * NN + ssrc[e]], sinv[ssrc[e]] * sinv[sdst[e]]);
    __syncthreads();
    for (int i = tid; i < 128 * 128; i += blockDim.x) {
        int r = i >> 7, c = i & 127;
        AbG[i] = (r < NN && c < NN) ? f2bf(Adense[r * NN + c]) : (unsigned short)0;
    }
    for (int j = tid; j < FD; j += blockDim.x) {
        bias0[j] = bih0[j] + bhh0[j];
        bias1[j] = bih1[j] + bhh1[j];
    }
}

// ---------------------------------------------------------------------------
// W (K=128 x N=128, fp32) -> bf16 [n][k] (k contiguous) for MFMA B-frags
// ---------------------------------------------------------------------------
__global__ void convw_kernel(const float* __restrict__ W, unsigned short* __restrict__ out) {
    int i = blockIdx.x * 512 + threadIdx.x;  // 16384 total
    int n = i >> 7, k = i & 127;
    out[i] = f2bf(W[k * DD + n]);
}

// ---------------------------------------------------------------------------
// Whh (512x128 fp32, rows j=g*128+d) -> f16 pairs for the quad-K-split scan:
// out[(g*16+q)*512 + d*4 + quarter] = pack(W[g*128+d][32*quarter+2q], [+2q+1])
// Thread j = 4d+quarter then loads wreg[g][q] = Wc[(g*16+q)*512 + j] coalesced.
// ---------------------------------------------------------------------------
__global__ void convh_kernel(const float* __restrict__ W, unsigned int* __restrict__ out) {
    int i = blockIdx.x * 512 + threadIdx.x;  // 32768 total
    int j = i & 511;
    int quarter = j & 3, d = j >> 2;
    int gq = i >> 9;            // 0..63
    int q = gq & 15, g = gq >> 4;
    const float* row = W + (size_t)(g * 128 + d) * 128 + quarter * 32;
    float a = row[2 * q], b = row[2 * q + 1];
    unsigned short lo = __builtin_bit_cast(unsigned short, (_Float16)a);
    unsigned short hi = __builtin_bit_cast(unsigned short, (_Float16)b);
    out[i] = (unsigned int)lo | ((unsigned int)hi << 16);
}

// ---------------------------------------------------------------------------
// Wih (512x128) -> WT [k=128][j=512] so proj reads coalesced
// ---------------------------------------------------------------------------
__global__ void transpose_kernel(const float* __restrict__ in, float* __restrict__ out) {
    int idx = blockIdx.x * blockDim.x + threadIdx.x;  // 65536 total
    int j = idx >> 7, k = idx & 127;
    out[k * FD + j] = in[idx];
}

// ---------------------------------------------------------------------------
// GCN building blocks (unchanged since round 5)
// ---------------------------------------------------------------------------
__device__ __forceinline__ void load_m(const unsigned short* __restrict__ src,
                                       unsigned short* __restrict__ dst, int tid) {
    const uint4* s4 = (const uint4*)src;  // 2048 chunks of 16B (8 bf16)
    for (int c = tid; c < 2048; c += 512) {
        int r = c >> 4, k8 = (c & 15) * 8;
        uint4 v = s4[c];
        *(uint4*)(dst + r * XS + k8) = v;
    }
}

// mm1: hS[n=dout][m=node] = (xb[m][k] @ wt[n][k]) packed bf16
__device__ __forceinline__ void mm_xw(const unsigned short* __restrict__ xb,
                                      const unsigned short* __restrict__ wt,
                                      unsigned short* __restrict__ hS, int tid) {
    int lane = tid & 63, w = tid >> 6;
    int lm = lane & 15, lq = lane >> 4;
    int wm = (w & 1) * 64, wn = (w >> 1) * 32;
    f32x4 acc[4][2];
#pragma unroll
    for (int mt = 0; mt < 4; ++mt)
#pragma unroll
        for (int nt = 0; nt < 2; ++nt) acc[mt][nt] = (f32x4){0.f, 0.f, 0.f, 0.f};
#pragma unroll
    for (int kb = 0; kb < 4; ++kb) {
        int ko = kb * 32 + lq * 8;
        bf16x8 b0 = *(const bf16x8*)(wt + (wn + lm) * XS + ko);
        bf16x8 b1 = *(const bf16x8*)(wt + (wn + 16 + lm) * XS + ko);
#pragma unroll
        for (int mt = 0; mt < 4; ++mt) {
            bf16x8 af = *(const bf16x8*)(xb + (wm + mt * 16 + lm) * XS + ko);
            acc[mt][0] = __builtin_amdgcn_mfma_f32_16x16x32_bf16(af, b0, acc[mt][0], 0, 0, 0);
            acc[mt][1] = __builtin_amdgcn_mfma_f32_16x16x32_bf16(af, b1, acc[mt][1], 0, 0, 0);
        }
    }
#pragma unroll
    for (int mt = 0; mt < 4; ++mt)
#pragma unroll
        for (int nt = 0; nt < 2; ++nt) {
            f32x4 a = acc[mt][nt];
            ushort4 pk;
            pk.x = f2bf(a[0]); pk.y = f2bf(a[1]); pk.z = f2bf(a[2]); pk.w = f2bf(a[3]);
            *(ushort4*)(hS + (wn + nt * 16 + lm) * XS + wm + mt * 16 + lq * 4) = pk;
        }
}

// mm2: xb[m=node][n=d] = silu(Ab[m][k] @ hS[n][k] + bias[n]) bf16
__device__ __forceinline__ void mm_agg(const unsigned short* __restrict__ Ab,
                                       const unsigned short* __restrict__ hS,
                                       unsigned short* __restrict__ xb,
                                       float bn0, float bn1, int tid) {
    int lane = tid & 63, w = tid >> 6;
    int lm = lane & 15, lq = lane >> 4;
    int wm = (w & 1) * 64, wn = (w >> 1) * 32;
    f32x4 acc[4][2];
#pragma unroll
    for (int mt = 0; mt < 4; ++mt)
#pragma unroll
        for (int nt = 0; nt < 2; ++nt) acc[mt][nt] = (f32x4){0.f, 0.f, 0.f, 0.f};
#pragma unroll
    for (int kb = 0; kb < 4; ++kb) {
        int ko = kb * 32 + lq * 8;
        bf16x8 b0 = *(const bf16x8*)(hS + (wn + lm) * XS + ko);
        bf16x8 b1 = *(const bf16x8*)(hS + (wn + 16 + lm) * XS + ko);
#pragma unroll
        for (int mt = 0; mt < 4; ++mt) {
            bf16x8 af = *(const bf16x8*)(Ab + (wm + mt * 16 + lm) * XS + ko);
            acc[mt][0] = __builtin_amdgcn_mfma_f32_16x16x32_bf16(af, b0, acc[mt][0], 0, 0, 0);
            acc[mt][1] = __builtin_amdgcn_mfma_f32_16x16x32_bf16(af, b1, acc[mt][1], 0, 0, 0);
        }
    }
#pragma unroll
    for (int mt = 0; mt < 4; ++mt)
#pragma unroll
        for (int nt = 0; nt < 2; ++nt) {
            float bn = nt ? bn1 : bn0;
            int col = wn + nt * 16 + lm;
#pragma unroll
            for (int i = 0; i < 4; ++i) {
                float v = silu_f(acc[mt][nt][i] + bn);
                xb[(wm + mt * 16 + lq * 4 + i) * XS + col] = f2bf(v);
            }
        }
}

__global__ __launch_bounds__(512) void gcn_kernel(
    const float* __restrict__ xg, const float* __restrict__ scale, const float* __restrict__ shift,
    const float* __restrict__ W1, const float* __restrict__ b1,
    const float* __restrict__ b2, const float* __restrict__ b3,
    const unsigned short* __restrict__ AbG,
    const unsigned short* __restrict__ Wt2g, const unsigned short* __restrict__ Wt3g,
    float* __restrict__ emb) {
    extern __shared__ char smem[];
    unsigned short* xb = (unsigned short*)smem;              // 34816 B  [node][d]
    unsigned short* hS = (unsigned short*)(smem + 34816);    // 34816 B  [d][node]
    unsigned short* Ab = (unsigned short*)(smem + 69632);    // 34816 B  [dst][src]
    unsigned short* wt = (unsigned short*)(smem + 104448);   // 34816 B  [dout][din]
    float* xinL  = (float*)(smem + 139264);                  // 354 f
    float* meanS = (float*)(smem + 140688);                  // 512 f (end 142736)
    int tid = threadIdx.x;
    int lane = tid & 63, w = tid >> 6;
    int g = blockIdx.x;

    for (int i = tid; i < 2176; i += 512) ((uint4*)hS)[i] = (uint4){0, 0, 0, 0};
    for (int i = tid; i < 170; i += 512) ((uint4*)(xb + NN * XS))[i] = (uint4){0, 0, 0, 0};
    float s0 = scale[0], s1 = scale[1], s2 = scale[2];
    float t0 = shift[0], t1 = shift[1], t2 = shift[2];
    const float* xrow = xg + (size_t)g * (NN * 3);
    for (int i = tid; i < NN * 3; i += 512) {
        int f = i % 3;
        float sc = (f == 0) ? s0 : ((f == 1) ? s1 : s2);
        float sf = (f == 0) ? t0 : ((f == 1) ? t1 : t2);
        xinL[i] = xrow[i] * sc + sf;
    }
    load_m(AbG, Ab, tid);
    load_m(Wt2g, wt, tid);
    int lm = lane & 15;
    int wn = (w >> 1) * 32;
    int n0 = wn + lm, n1 = wn + 16 + lm;
    float b1a = b1[n0], b1b = b1[n1];
    float b2a = b2[n0], b2b = b2[n1];
    float b3a = b3[n0], b3b = b3[n1];
    int dd = lane * 2;
    float2 w10 = *(const float2*)(W1 + dd);
    float2 w11 = *(const float2*)(W1 + DD + dd);
    float2 w12 = *(const float2*)(W1 + 2 * DD + dd);
    bar_lds();
    for (int k = 0; k < 15; ++k) {
        int n = w + 8 * k;
        if (n >= NN) break;
        float x0 = xinL[n * 3], x1 = xinL[n * 3 + 1], x2 = xinL[n * 3 + 2];
        hS[dd * XS + n]       = f2bf(x0 * w10.x + x1 * w11.x + x2 * w12.x);
        hS[(dd + 1) * XS + n] = f2bf(x0 * w10.y + x1 * w11.y + x2 * w12.y);
    }
    bar_lds();
    mm_agg(Ab, hS, xb, b1a, b1b, tid);   // x1
    bar_lds();
    mm_xw(xb, wt, hS, tid);              // h2
    bar_lds();
    load_m(Wt3g, wt, tid);
    mm_agg(Ab, hS, xb, b2a, b2b, tid);   // x2
    bar_lds();
    mm_xw(xb, wt, hS, tid);              // h3
    bar_lds();
    mm_agg(Ab, hS, xb, b3a, b3b, tid);   // x3
    bar_lds();
    {
        int d = tid & 127, part = tid >> 7;
        int a0 = part * 30;
        int a1 = (a0 + 30 < NN) ? (a0 + 30) : NN;
        float s = 0.f;
        for (int n = a0; n < a1; ++n) s += bf2f(xb[n * XS + d]);
        meanS[part * 128 + d] = s;
    }
    bar_lds();
    if (tid < 128) {
        float s = meanS[tid] + meanS[128 + tid] + meanS[256 + tid] + meanS[384 + tid];
        emb[(size_t)g * DD + tid] = s * (1.0f / (float)NN);
    }
}

// ---------------------------------------------------------------------------
// proj: dst[g][j] = bias[j] + sum_k src[g][k] * WT[k][j]
// ---------------------------------------------------------------------------
__global__ __launch_bounds__(512) void proj_kernel(const float* __restrict__ src,
                                                   const float* __restrict__ WT,
                                                   const float* __restrict__ bias,
                                                   float* __restrict__ dst) {
    __shared__ __align__(16) float eL[DD];
    int g = blockIdx.x, tid = threadIdx.x;
    if (tid < DD) eL[tid] = src[(size_t)g * DD + tid];
    __syncthreads();
    float acc = bias[tid];
    const float* wt = WT + tid;
#pragma unroll 8
    for (int k = 0; k < DD; ++k) acc += eL[k] * wt[(size_t)k * FD];
    dst[(size_t)g * FD + tid] = acc;
}

// ---------------------------------------------------------------------------
// LSTM scan, quad-K-split: 512 threads/block, thread j = (quarter=j&3, d=j>>2)
// owns all 4 gate rows of dim d over K in [32*quarter, +32) -> 64 weight regs
// (scalar asm-pinned; r7/r10 tuple pins failed, r8 256-reg spilled).
// The 4 threads sharing d are ADJACENT LANES (one quad): the K-split partials
// reduce via 2 butterfly __shfl_xor steps -- no LDS partials, no 2nd barrier.
// h double-buffered in LDS -> ONE lgkm-only barrier per step (r11 had two
// barriers + an LDS partial round-trip; 3 configs all plateaued ~1375 cyc/step
// => latency-chain-bound, so cut chain stages).
// ---------------------------------------------------------------------------
__global__ __launch_bounds__(512, 2) void scan_kernel(
    const float* __restrict__ inp,          // [B][T][512] gate-major (bias incl)
    const unsigned int* __restrict__ Wc,    // [(g*16+q)][j=4d+quarter] f16 pairs
    float* __restrict__ hout, int full) {
    __shared__ __align__(16) unsigned short hL[2][DD];  // h as f16, double-buffered
    int b = blockIdx.x, j = threadIdx.x;
    int quarter = j & 3, d = j >> 2;
    unsigned int wreg[4][16];
#pragma unroll
    for (int g = 0; g < 4; ++g)
#pragma unroll
        for (int q = 0; q < 16; ++q)
            wreg[g][q] = Wc[(g * 16 + q) * 512 + j];   // coalesced
    // pin scalars: asm-defined values cannot be rematerialized into the loop
#pragma unroll
    for (int g = 0; g < 4; ++g)
#pragma unroll
        for (int q = 0; q < 16; ++q)
            asm volatile("" : "+v"(wreg[g][q]));
    if (j < 128) ((unsigned int*)hL)[j] = 0u;   // zero both buffers
    float creg = 0.f;
    const float* ib = inp + (size_t)b * TT * FD;
    float* hb_ = hout + (size_t)b * (full ? TT * DD : DD);
    float xg0[4], xg1[4];
    if (quarter == 0) {
#pragma unroll
        for (int g = 0; g < 4; ++g) { xg0[g] = ib[g * DD + d]; xg1[g] = ib[FD + g * DD + d]; }
    }
    bar_lds();
    for (int t = 0; t < TT; ++t) {
        float xg2[4];
        if (quarter == 0) {
            bool more = (t + 2 < TT);
#pragma unroll
            for (int g = 0; g < 4; ++g)
                xg2[g] = more ? ib[(t + 2) * FD + g * DD + d] : 0.f;  // prefetch depth 2
        }
        // read this quarter's h slice (broadcast within the 128 threads/quarter)
        const uint4* h4 = (const uint4*)(hL[t & 1] + quarter * 32);
        float a0 = 0.f, a1 = 0.f, a2 = 0.f, a3 = 0.f;
#pragma unroll
        for (int c = 0; c < 4; ++c) {
            uint4 hv = h4[c];
            a0 = fdot2_(wreg[0][4 * c + 0], hv.x, a0);
            a1 = fdot2_(wreg[1][4 * c + 0], hv.x, a1);
            a2 = fdot2_(wreg[2][4 * c + 0], hv.x, a2);
            a3 = fdot2_(wreg[3][4 * c + 0], hv.x, a3);
            a0 = fdot2_(wreg[0][4 * c + 1], hv.y, a0);
            a1 = fdot2_(wreg[1][4 * c + 1], hv.y, a1);
            a2 = fdot2_(wreg[2][4 * c + 1], hv.y, a2);
            a3 = fdot2_(wreg[3][4 * c + 1], hv.y, a3);
            a0 = fdot2_(wreg[0][4 * c + 2], hv.z, a0);
            a1 = fdot2_(wreg[1][4 * c + 2], hv.z, a1);
            a2 = fdot2_(wreg[2][4 * c + 2], hv.z, a2);
            a3 = fdot2_(wreg[3][4 * c + 2], hv.z, a3);
            a0 = fdot2_(wreg[0][4 * c + 3], hv.w, a0);
            a1 = fdot2_(wreg[1][4 * c + 3], hv.w, a1);
            a2 = fdot2_(wreg[2][4 * c + 3], hv.w, a2);
            a3 = fdot2_(wreg[3][4 * c + 3], hv.w, a3);
        }
        // quad butterfly: sum the 4 K-quarter partials across adjacent lanes
        a0 += __shfl_xor(a0, 1); a0 += __shfl_xor(a0, 2);
        a1 += __shfl_xor(a1, 1); a1 += __shfl_xor(a1, 2);
        a2 += __shfl_xor(a2, 1); a2 += __shfl_xor(a2, 2);
        a3 += __shfl_xor(a3, 1); a3 += __shfl_xor(a3, 2);
        if (quarter == 0) {
            float iv = sig_f(a0 + xg0[0]);
            float fv = sig_f(a1 + xg0[1]);
            float gv = tanh_f(a2 + xg0[2]);
            float ov = sig_f(a3 + xg0[3]);
            float cn = fv * creg + iv * gv;
            creg = cn;
            float hn = ov * tanh_f(cn);
            ((_Float16*)hL[(t + 1) & 1])[d] = (_Float16)hn;
            if (full) hb_[t * DD + d] = hn;           // fire-and-forget
            else if (t == TT - 1) hb_[d] = hn;
#pragma unroll
            for (int g = 0; g < 4; ++g) { xg0[g] = xg1[g]; xg1[g] = xg2[g]; }
        }
        bar_lds();
    }
}

// ---------------------------------------------------------------------------
// head MLP on final hidden state. 1 block.
// ---------------------------------------------------------------------------
__global__ void head_kernel(const float* __restrict__ hfin,
                            const float* __restrict__ hW1, const float* __restrict__ hb1,
                            const float* __restrict__ hW2, const float* __restrict__ hb2,
                            const float* __restrict__ hW3, const float* __restrict__ hb3,
                            float* __restrict__ out) {
    __shared__ float fh[BB * DD];
    __shared__ float y1[BB * DD];
    __shared__ float y2[BB * 64];
    int tid = threadIdx.x;
    for (int i = tid; i < BB * DD; i += 256) fh[i] = hfin[i];
    __syncthreads();
    for (int i = tid; i < BB * DD; i += 256) {
        int bb = i >> 7, jj = i & 127;
        float acc = hb1[jj];
        for (int k = 0; k < DD; ++k) acc += fh[(bb << 7) + k] * hW1[(k << 7) + jj];
        y1[i] = siluf_(acc);
    }
    __syncthreads();
    for (int i = tid; i < BB * 64; i += 256) {
        int bb = i >> 6, jj = i & 63;
        float acc = hb2[jj];
        for (int k = 0; k < DD; ++k) acc += y1[(bb << 7) + k] * hW2[(k << 6) + jj];
        y2[i] = siluf_(acc);
    }
    __syncthreads();
    if (tid < BB * 2) {
        int bb = tid >> 1, m = tid & 1;
        float acc = hb3[m];
        for (int k = 0; k < 64; ++k) acc += y2[(bb << 6) + k] * hW3[k * 2 + m];
        float sp = fmaxf(acc, 0.f) + log1pf(expf(-fabsf(acc)));
        out[tid] = sp + 1e-6f;
    }
}

// ---------------------------------------------------------------------------
extern "C" void kernel_launch(void* const* d_in, const int* in_sizes, int n_in,
                              void* d_out, int out_size, void* d_ws, size_t ws_size,
                              hipStream_t stream) {
    const float* snap  = (const float*)d_in[0];
    const int*   edges = (const int*)d_in[1];
    const float* scale = (const float*)d_in[2];
    const float* shift = (const float*)d_in[3];
    const float* W1 = (const float*)d_in[4];
    const float* b1 = (const float*)d_in[5];
    const float* W2 = (const float*)d_in[6];
    const float* b2 = (const float*)d_in[7];
    const float* W3 = (const float*)d_in[8];
    const float* b3 = (const float*)d_in[9];
    const float* Wih0 = (const float*)d_in[10];
    const float* Whh0 = (const float*)d_in[11];
    const float* bih0 = (const float*)d_in[12];
    const float* bhh0 = (const float*)d_in[13];
    const float* Wih1 = (const float*)d_in[14];
    const float* Whh1 = (const float*)d_in[15];
    const float* bih1 = (const float*)d_in[16];
    const float* bhh1 = (const float*)d_in[17];
    const float* hW1 = (const float*)d_in[18];
    const float* hb1 = (const float*)d_in[19];
    const float* hW2 = (const float*)d_in[20];
    const float* hb2 = (const float*)d_in[21];
    const float* hW3 = (const float*)d_in[22];
    const float* hb3 = (const float*)d_in[23];

    // workspace carve (float indices); ~7.2 MB
    float* ws = (float*)d_ws;
    float* bias0 = ws + 0;                        // 512
    float* bias1 = ws + 512;                      // 512
    unsigned short* AbG  = (unsigned short*)(ws + 1024);   // 8192 f
    unsigned short* Wt2g = (unsigned short*)(ws + 9216);   // 8192 f
    unsigned short* Wt3g = (unsigned short*)(ws + 17408);  // 8192 f
    float* WT0 = ws + 25600;                      // 65536
    float* WT1 = ws + 91136;                      // 65536
    unsigned int* Wc0 = (unsigned int*)(ws + 156672);      // 32768
    unsigned int* Wc1 = (unsigned int*)(ws + 189440);      // 32768
    float* emb   = ws + 222208;                   // 262144
    float* inp   = ws + 484352;                   // 1048576 (both LSTM layers)
    float* h0seq = ws + 1532928;                  // 262144
    float* hfin  = ws + 1795072;                  // 1024

    const int smem_gcn = 142736;
    hipFuncSetAttribute((const void*)gcn_kernel,
                        hipFuncAttributeMaxDynamicSharedMemorySize, smem_gcn);

    prep_kernel<<<1, 256, 0, stream>>>(edges, bih0, bhh0, bih1, bhh1,
                                       bias0, bias1, AbG);
    convw_kernel<<<32, 512, 0, stream>>>(W2, Wt2g);
    convw_kernel<<<32, 512, 0, stream>>>(W3, Wt3g);
    convh_kernel<<<64, 512, 0, stream>>>(Whh0, Wc0);
    convh_kernel<<<64, 512, 0, stream>>>(Whh1, Wc1);
    transpose_kernel<<<128, 512, 0, stream>>>(Wih0, WT0);
    transpose_kernel<<<128, 512, 0, stream>>>(Wih1, WT1);
    gcn_kernel<<<GG, 512, smem_gcn, stream>>>(snap, scale, shift, W1, b1, b2, b3,
                                              AbG, Wt2g, Wt3g, emb);
    proj_kernel<<<GG, 512, 0, stream>>>(emb, WT0, bias0, inp);
    scan_kernel<<<BB, 512, 0, stream>>>(inp, Wc0, h0seq, 1);
    proj_kernel<<<GG, 512, 0, stream>>>(h0seq, WT1, bias1, inp);
    scan_kernel<<<BB, 512, 0, stream>>>(inp, Wc1, hfin, 0);
    head_kernel<<<1, 256, 0, stream>>>(hfin, hW1, hb1, hW2, hb2, hW3, hb3, (float*)d_out);
}

// Round 13
// 627.068 us; speedup vs baseline: 1.0415x; 1.0415x over previous
//
#include <hip/hip_runtime.h>
#include <math.h>

// Problem constants
#define NN 118   // nodes
#define EE 372   // edges
#define GG 2048  // B*T
#define DD 128   // hidden
#define TT 256   // seq len
#define BB 8     // batch
#define FD 512   // 4*D

// LDS stride for bf16 matrices (rows 16B-aligned, 2-way-max bank aliasing)
#define XS 136

typedef short bf16x8 __attribute__((ext_vector_type(8)));
typedef float f32x4  __attribute__((ext_vector_type(4)));
typedef _Float16 f16x2 __attribute__((ext_vector_type(2)));

__device__ __forceinline__ float frcp_(float x) { return __builtin_amdgcn_rcpf(x); }
__device__ __forceinline__ float sig_f(float x) { return frcp_(1.0f + __expf(-x)); }
__device__ __forceinline__ float tanh_f(float x) { return 1.0f - 2.0f * frcp_(__expf(2.0f * x) + 1.0f); }
__device__ __forceinline__ float silu_f(float x) { return x * frcp_(1.0f + __expf(-x)); }
__device__ __forceinline__ float siluf_(float x) { return x / (1.0f + expf(-x)); }

// f16-pair dot with fp32 accumulate (v_dot2_f32_f16); scalar fallback.
__device__ __forceinline__ float fdot2_(unsigned int a, unsigned int b, float c) {
#if defined(__has_builtin) && __has_builtin(__builtin_amdgcn_fdot2)
    return __builtin_amdgcn_fdot2(__builtin_bit_cast(f16x2, a),
                                  __builtin_bit_cast(f16x2, b), c, false);
#else
    f16x2 x = __builtin_bit_cast(f16x2, a), y = __builtin_bit_cast(f16x2, b);
    return c + (float)x[0] * (float)y[0] + (float)x[1] * (float)y[1];
#endif
}

// Barrier draining only LDS ops (lgkmcnt), not vmcnt: global stores stay
// fire-and-forget, prefetch loads stay in flight. Safe: all cross-thread data
// flows through LDS (global->VGPR uses get compiler vmcnt waits).
__device__ __forceinline__ void bar_lds() {
    asm volatile("s_waitcnt lgkmcnt(0)\n\ts_barrier" ::: "memory");
}

__device__ __forceinline__ unsigned short f2bf(float x) {
    unsigned int u = __float_as_uint(x);
    unsigned int r = (u + 0x7fffu + ((u >> 16) & 1u)) >> 16;
    return (unsigned short)r;
}
__device__ __forceinline__ float bf2f(unsigned short b) {
    return __uint_as_float(((unsigned int)b) << 16);
}

// ---------------------------------------------------------------------------
// prep: dense normalized adjacency A -> bf16 128x128 (zero padded), fused
// LSTM biases (plain gate-major order). 1 block.
// ---------------------------------------------------------------------------
__global__ void prep_kernel(const int* __restrict__ ei,
                            const float* __restrict__ bih0, const float* __restrict__ bhh0,
                            const float* __restrict__ bih1, const float* __restrict__ bhh1,
                            float* __restrict__ bias0, float* __restrict__ bias1,
                            unsigned short* __restrict__ AbG) {
    __shared__ int sflag;
    __shared__ int ssrc[EE], sdst[EE];
    __shared__ int scount[NN];
    __shared__ float sinv[NN];
    __shared__ float Adense[NN * NN];  // 55.7 KB
    int tid = threadIdx.x;
    if (tid == 0) sflag = 0;
    __syncthreads();
    // int64-vs-int32 layout detect (values < 118 -> high words zero if int64)
    for (int i = tid; i < 2 * EE; i += blockDim.x)
        if ((i & 1) && ei[i] != 0) atomicOr(&sflag, 1);
    __syncthreads();
    bool m64 = (sflag == 0);
    for (int e = tid; e < EE; e += blockDim.x) {
        int s, d;
        if (m64) { s = ei[2 * e]; d = ei[2 * EE + 2 * e]; }
        else     { s = ei[e];     d = ei[EE + e]; }
        s = min(max(s, 0), NN - 1); d = min(max(d, 0), NN - 1);
        ssrc[e] = s; sdst[e] = d;
    }
    for (int n = tid; n < NN; n += blockDim.x) scount[n] = 0;
    for (int i = tid; i < NN * NN; i += blockDim.x) Adense[i] = 0.0f;
    __syncthreads();
    for (int e = tid; e < EE; e += blockDim.x) atomicAdd(&scount[sdst[e]], 1);
    __syncthreads();
    for (int n = tid; n < NN; n += blockDim.x) {
        float deg = 1.0f + (float)scount[n];
        sinv[n] = rsqrtf(deg);
        Adense[n * NN + n] = 1.0f / deg;   // self term h*(1/deg)
    }
    __syncthreads();
    for (int e = tid; e < EE; e += blockDim.x)
        atomicAdd(&Adense[sdst[e] * NN + ssrc[e]], sinv[ssrc[e]] * sinv[sdst[e]]);
    __syncthreads();
    for (int i = tid; i < 128 * 128; i += blockDim.x) {
        int r = i >> 7, c = i & 127;
        AbG[i] = (r < NN && c < NN) ? f2bf(Adense[r * NN + c]) : (unsigned short)0;
    }
    for (int j = tid; j < FD; j += blockDim.x) {
        bias0[j] = bih0[j] + bhh0[j];
        bias1[j] = bih1[j] + bhh1[j];
    }
}

// ---------------------------------------------------------------------------
// W (K=128 x N=128, fp32) -> bf16 [n][k] (k contiguous) for MFMA B-frags
// ---------------------------------------------------------------------------
__global__ void convw_kernel(const float* __restrict__ W, unsigned short* __restrict__ out) {
    int i = blockIdx.x * 512 + threadIdx.x;  // 16384 total
    int n = i >> 7, k = i & 127;
    out[i] = f2bf(W[k * DD + n]);
}

// ---------------------------------------------------------------------------
// Whh (512x128 fp32, rows j=g*128+d) -> f16 pairs for the K-split-4 scan:
// out[(((g*16+q)*4)+quarter)*128 + d] = pack(W[g*128+d][32*quarter+2q], [+2q+1])
// (round-11 layout; thread (quarter,d) loads (g,q) with consecutive-d coalescing)
// ---------------------------------------------------------------------------
__global__ void convh_kernel(const float* __restrict__ W, unsigned int* __restrict__ out) {
    int i = blockIdx.x * 512 + threadIdx.x;  // 32768 total
    int d = i & 127;
    int rest = i >> 7;          // 0..255
    int quarter = rest & 3;
    int qg = rest >> 2;         // 0..63
    int q = qg & 15, g = qg >> 4;
    const float* row = W + (size_t)(g * 128 + d) * 128 + quarter * 32;
    float a = row[2 * q], b = row[2 * q + 1];
    unsigned short lo = __builtin_bit_cast(unsigned short, (_Float16)a);
    unsigned short hi = __builtin_bit_cast(unsigned short, (_Float16)b);
    out[i] = (unsigned int)lo | ((unsigned int)hi << 16);
}

// ---------------------------------------------------------------------------
// Wih (512x128) -> WT [k=128][j=512] so proj reads coalesced
// ---------------------------------------------------------------------------
__global__ void transpose_kernel(const float* __restrict__ in, float* __restrict__ out) {
    int idx = blockIdx.x * blockDim.x + threadIdx.x;  // 65536 total
    int j = idx >> 7, k = idx & 127;
    out[k * FD + j] = in[idx];
}

// ---------------------------------------------------------------------------
// GCN building blocks. Round-13 change: A (adjacency) and W (weights) MFMA
// operands are read STRAIGHT FROM GLOBAL (block-invariant 32KB each, L2-hot
// across all 2048 blocks) instead of being staged in LDS. LDS drops
// 142.7KB -> 73KB => 2 blocks/CU (was 1): doubles latency hiding across the
// 7 barrier-separated phases, removes 3 load_m staging passes.
// ---------------------------------------------------------------------------
// mm1: hS[n=dout][m=node] = (xb[m][k] @ wtG[n][k]) packed bf16 (wtG global)
__device__ __forceinline__ void mm_xw(const unsigned short* __restrict__ xb,
                                      const unsigned short* __restrict__ wtG,
                                      unsigned short* __restrict__ hS, int tid) {
    int lane = tid & 63, w = tid >> 6;
    int lm = lane & 15, lq = lane >> 4;
    int wm = (w & 1) * 64, wn = (w >> 1) * 32;
    f32x4 acc[4][2];
#pragma unroll
    for (int mt = 0; mt < 4; ++mt)
#pragma unroll
        for (int nt = 0; nt < 2; ++nt) acc[mt][nt] = (f32x4){0.f, 0.f, 0.f, 0.f};
#pragma unroll
    for (int kb = 0; kb < 4; ++kb) {
        int ko = kb * 32 + lq * 8;
        bf16x8 b0 = *(const bf16x8*)(wtG + (wn + lm) * 128 + ko);        // global, L2-hot
        bf16x8 b1 = *(const bf16x8*)(wtG + (wn + 16 + lm) * 128 + ko);
#pragma unroll
        for (int mt = 0; mt < 4; ++mt) {
            bf16x8 af = *(const bf16x8*)(xb + (wm + mt * 16 + lm) * XS + ko);
            acc[mt][0] = __builtin_amdgcn_mfma_f32_16x16x32_bf16(af, b0, acc[mt][0], 0, 0, 0);
            acc[mt][1] = __builtin_amdgcn_mfma_f32_16x16x32_bf16(af, b1, acc[mt][1], 0, 0, 0);
        }
    }
#pragma unroll
    for (int mt = 0; mt < 4; ++mt)
#pragma unroll
        for (int nt = 0; nt < 2; ++nt) {
            f32x4 a = acc[mt][nt];
            ushort4 pk;
            pk.x = f2bf(a[0]); pk.y = f2bf(a[1]); pk.z = f2bf(a[2]); pk.w = f2bf(a[3]);
            *(ushort4*)(hS + (wn + nt * 16 + lm) * XS + wm + mt * 16 + lq * 4) = pk;
        }
}

// mm2: xb[m=node][n=d] = silu(AbG[m][k] @ hS[n][k] + bias[n]) bf16 (AbG global)
__device__ __forceinline__ void mm_agg(const unsigned short* __restrict__ AbG,
                                       const unsigned short* __restrict__ hS,
                                       unsigned short* __restrict__ xb,
                                       float bn0, float bn1, int tid) {
    int lane = tid & 63, w = tid >> 6;
    int lm = lane & 15, lq = lane >> 4;
    int wm = (w & 1) * 64, wn = (w >> 1) * 32;
    f32x4 acc[4][2];
#pragma unroll
    for (int mt = 0; mt < 4; ++mt)
#pragma unroll
        for (int nt = 0; nt < 2; ++nt) acc[mt][nt] = (f32x4){0.f, 0.f, 0.f, 0.f};
#pragma unroll
    for (int kb = 0; kb < 4; ++kb) {
        int ko = kb * 32 + lq * 8;
        bf16x8 b0 = *(const bf16x8*)(hS + (wn + lm) * XS + ko);
        bf16x8 b1 = *(const bf16x8*)(hS + (wn + 16 + lm) * XS + ko);
#pragma unroll
        for (int mt = 0; mt < 4; ++mt) {
            bf16x8 af = *(const bf16x8*)(AbG + (wm + mt * 16 + lm) * 128 + ko);  // global, L2-hot
            acc[mt][0] = __builtin_amdgcn_mfma_f32_16x16x32_bf16(af, b0, acc[mt][0], 0, 0, 0);
            acc[mt][1] = __builtin_amdgcn_mfma_f32_16x16x32_bf16(af, b1, acc[mt][1], 0, 0, 0);
        }
    }
#pragma unroll
    for (int mt = 0; mt < 4; ++mt)
#pragma unroll
        for (int nt = 0; nt < 2; ++nt) {
            float bn = nt ? bn1 : bn0;
            int col = wn + nt * 16 + lm;
#pragma unroll
            for (int i = 0; i < 4; ++i) {
                float v = silu_f(acc[mt][nt][i] + bn);
                xb[(wm + mt * 16 + lq * 4 + i) * XS + col] = f2bf(v);
            }
        }
}

__global__ __launch_bounds__(512) void gcn_kernel(
    const float* __restrict__ xg, const float* __restrict__ scale, const float* __restrict__ shift,
    const float* __restrict__ W1, const float* __restrict__ b1,
    const float* __restrict__ b2, const float* __restrict__ b3,
    const unsigned short* __restrict__ AbG,
    const unsigned short* __restrict__ Wt2g, const unsigned short* __restrict__ Wt3g,
    float* __restrict__ emb) {
    extern __shared__ char smem[];
    unsigned short* xb = (unsigned short*)smem;              // 34816 B  [node][d]
    unsigned short* hS = (unsigned short*)(smem + 34816);    // 34816 B  [d][node]
    float* xinL  = (float*)(smem + 69632);                   // 354 f -> 1424 B
    float* meanS = (float*)(smem + 71056);                   // 512 f -> 2048 B (end 73104)
    int tid = threadIdx.x;
    int lane = tid & 63, w = tid >> 6;
    int g = blockIdx.x;

    for (int i = tid; i < 2176; i += 512) ((uint4*)hS)[i] = (uint4){0, 0, 0, 0};
    for (int i = tid; i < 170; i += 512) ((uint4*)(xb + NN * XS))[i] = (uint4){0, 0, 0, 0};
    float s0 = scale[0], s1 = scale[1], s2 = scale[2];
    float t0 = shift[0], t1 = shift[1], t2 = shift[2];
    const float* xrow = xg + (size_t)g * (NN * 3);
    for (int i = tid; i < NN * 3; i += 512) {
        int f = i % 3;
        float sc = (f == 0) ? s0 : ((f == 1) ? s1 : s2);
        float sf = (f == 0) ? t0 : ((f == 1) ? t1 : t2);
        xinL[i] = xrow[i] * sc + sf;
    }
    int lm = lane & 15;
    int wn = (w >> 1) * 32;
    int n0 = wn + lm, n1 = wn + 16 + lm;
    float b1a = b1[n0], b1b = b1[n1];
    float b2a = b2[n0], b2b = b2[n1];
    float b3a = b3[n0], b3b = b3[n1];
    int dd = lane * 2;
    float2 w10 = *(const float2*)(W1 + dd);
    float2 w11 = *(const float2*)(W1 + DD + dd);
    float2 w12 = *(const float2*)(W1 + 2 * DD + dd);
    bar_lds();
    for (int k = 0; k < 15; ++k) {
        int n = w + 8 * k;
        if (n >= NN) break;
        float x0 = xinL[n * 3], x1 = xinL[n * 3 + 1], x2 = xinL[n * 3 + 2];
        hS[dd * XS + n]       = f2bf(x0 * w10.x + x1 * w11.x + x2 * w12.x);
        hS[(dd + 1) * XS + n] = f2bf(x0 * w10.y + x1 * w11.y + x2 * w12.y);
    }
    bar_lds();
    mm_agg(AbG, hS, xb, b1a, b1b, tid);   // x1
    bar_lds();
    mm_xw(xb, Wt2g, hS, tid);             // h2
    bar_lds();
    mm_agg(AbG, hS, xb, b2a, b2b, tid);   // x2
    bar_lds();
    mm_xw(xb, Wt3g, hS, tid);             // h3
    bar_lds();
    mm_agg(AbG, hS, xb, b3a, b3b, tid);   // x3
    bar_lds();
    {
        int d = tid & 127, part = tid >> 7;
        int a0 = part * 30;
        int a1 = (a0 + 30 < NN) ? (a0 + 30) : NN;
        float s = 0.f;
        for (int n = a0; n < a1; ++n) s += bf2f(xb[n * XS + d]);
        meanS[part * 128 + d] = s;
    }
    bar_lds();
    if (tid < 128) {
        float s = meanS[tid] + meanS[128 + tid] + meanS[256 + tid] + meanS[384 + tid];
        emb[(size_t)g * DD + tid] = s * (1.0f / (float)NN);
    }
}

// ---------------------------------------------------------------------------
// proj: dst[g][j] = bias[j] + sum_k src[g][k] * WT[k][j]
// ---------------------------------------------------------------------------
__global__ __launch_bounds__(512) void proj_kernel(const float* __restrict__ src,
                                                   const float* __restrict__ WT,
                                                   const float* __restrict__ bias,
                                                   float* __restrict__ dst) {
    __shared__ __align__(16) float eL[DD];
    int g = blockIdx.x, tid = threadIdx.x;
    if (tid < DD) eL[tid] = src[(size_t)g * DD + tid];
    __syncthreads();
    float acc = bias[tid];
    const float* wt = WT + tid;
#pragma unroll 8
    for (int k = 0; k < DD; ++k) acc += eL[k] * wt[(size_t)k * FD];
    dst[(size_t)g * FD + tid] = acc;
}

// ---------------------------------------------------------------------------
// LSTM scan (round-11 config, the scan plateau winner: 147 us/layer).
// K-split 4 via LDS partials, 64 scalar-pinned weight regs, 2 lgkm barriers.
// Seven structures tried (r6-r12); all >=147 us => serial-chain floor.
// ---------------------------------------------------------------------------
__global__ __launch_bounds__(512, 2) void scan_kernel(
    const float* __restrict__ inp,          // [B][T][512] gate-major (bias incl)
    const unsigned int* __restrict__ Wc,    // [(g*16+q)*4+quarter][d] f16 pairs
    float* __restrict__ hout, int full) {
    __shared__ __align__(16) unsigned short hL[DD];  // h as f16
    __shared__ __align__(16) float sgP[3 * DD * 4];  // quarters 1-3 partials
    int b = blockIdx.x, j = threadIdx.x;
    int d = j & 127, quarter = j >> 7;
    unsigned int wreg[4][16];
#pragma unroll
    for (int g = 0; g < 4; ++g)
#pragma unroll
        for (int q = 0; q < 16; ++q)
            wreg[g][q] = Wc[(((g * 16 + q) << 2) + quarter) * 128 + d];
    // pin scalars: asm-defined values cannot be rematerialized into the loop
#pragma unroll
    for (int g = 0; g < 4; ++g)
#pragma unroll
        for (int q = 0; q < 16; ++q)
            asm volatile("" : "+v"(wreg[g][q]));
    if (j < 64) ((unsigned int*)hL)[j] = 0u;
    float creg = 0.f;
    const float* ib = inp + (size_t)b * TT * FD;
    float* hb_ = hout + (size_t)b * (full ? TT * DD : DD);
    float xg0[4], xg1[4];
    if (quarter == 0) {
#pragma unroll
        for (int g = 0; g < 4; ++g) { xg0[g] = ib[g * DD + d]; xg1[g] = ib[FD + g * DD + d]; }
    }
    bar_lds();
    for (int t = 0; t < TT; ++t) {
        float xg2[4];
        if (quarter == 0) {
            bool more = (t + 2 < TT);
#pragma unroll
            for (int g = 0; g < 4; ++g)
                xg2[g] = more ? ib[(t + 2) * FD + g * DD + d] : 0.f;  // prefetch depth 2
        }
        const uint4* h4 = (const uint4*)(hL + quarter * 32);  // 4 chunks, wave-uniform
        float a0 = 0.f, a1 = 0.f, a2 = 0.f, a3 = 0.f;
#pragma unroll
        for (int c = 0; c < 4; ++c) {
            uint4 hv = h4[c];
            a0 = fdot2_(wreg[0][4 * c + 0], hv.x, a0);
            a1 = fdot2_(wreg[1][4 * c + 0], hv.x, a1);
            a2 = fdot2_(wreg[2][4 * c + 0], hv.x, a2);
            a3 = fdot2_(wreg[3][4 * c + 0], hv.x, a3);
            a0 = fdot2_(wreg[0][4 * c + 1], hv.y, a0);
            a1 = fdot2_(wreg[1][4 * c + 1], hv.y, a1);
            a2 = fdot2_(wreg[2][4 * c + 1], hv.y, a2);
            a3 = fdot2_(wreg[3][4 * c + 1], hv.y, a3);
            a0 = fdot2_(wreg[0][4 * c + 2], hv.z, a0);
            a1 = fdot2_(wreg[1][4 * c + 2], hv.z, a1);
            a2 = fdot2_(wreg[2][4 * c + 2], hv.z, a2);
            a3 = fdot2_(wreg[3][4 * c + 2], hv.z, a3);
            a0 = fdot2_(wreg[0][4 * c + 3], hv.w, a0);
            a1 = fdot2_(wreg[1][4 * c + 3], hv.w, a1);
            a2 = fdot2_(wreg[2][4 * c + 3], hv.w, a2);
            a3 = fdot2_(wreg[3][4 * c + 3], hv.w, a3);
        }
        if (quarter != 0)
            *(float4*)(sgP + ((quarter - 1) * DD + d) * 4) = make_float4(a0, a1, a2, a3);
        bar_lds();
        if (quarter == 0) {
            float4 p1 = *(const float4*)(sgP + d * 4);
            float4 p2 = *(const float4*)(sgP + (DD + d) * 4);
            float4 p3 = *(const float4*)(sgP + (2 * DD + d) * 4);
            float iv = sig_f(a0 + p1.x + p2.x + p3.x + xg0[0]);
            float fv = sig_f(a1 + p1.y + p2.y + p3.y + xg0[1]);
            float gv = tanh_f(a2 + p1.z + p2.z + p3.z + xg0[2]);
            float ov = sig_f(a3 + p1.w + p2.w + p3.w + xg0[3]);
            float cn = fv * creg + iv * gv;
            creg = cn;
            float hn = ov * tanh_f(cn);
            ((_Float16*)hL)[d] = (_Float16)hn;
            if (full) hb_[t * DD + d] = hn;           // fire-and-forget
            else if (t == TT - 1) hb_[d] = hn;
#pragma unroll
            for (int g = 0; g < 4; ++g) { xg0[g] = xg1[g]; xg1[g] = xg2[g]; }
        }
        bar_lds();
    }
}

// ---------------------------------------------------------------------------
// head MLP on final hidden state. 1 block.
// ---------------------------------------------------------------------------
__global__ void head_kernel(const float* __restrict__ hfin,
                            const float* __restrict__ hW1, const float* __restrict__ hb1,
                            const float* __restrict__ hW2, const float* __restrict__ hb2,
                            const float* __restrict__ hW3, const float* __restrict__ hb3,
                            float* __restrict__ out) {
    __shared__ float fh[BB * DD];
    __shared__ float y1[BB * DD];
    __shared__ float y2[BB * 64];
    int tid = threadIdx.x;
    for (int i = tid; i < BB * DD; i += 256) fh[i] = hfin[i];
    __syncthreads();
    for (int i = tid; i < BB * DD; i += 256) {
        int bb = i >> 7, jj = i & 127;
        float acc = hb1[jj];
        for (int k = 0; k < DD; ++k) acc += fh[(bb << 7) + k] * hW1[(k << 7) + jj];
        y1[i] = siluf_(acc);
    }
    __syncthreads();
    for (int i = tid; i < BB * 64; i += 256) {
        int bb = i >> 6, jj = i & 63;
        float acc = hb2[jj];
        for (int k = 0; k < DD; ++k) acc += y1[(bb << 7) + k] * hW2[(k << 6) + jj];
        y2[i] = siluf_(acc);
    }
    __syncthreads();
    if (tid < BB * 2) {
        int bb = tid >> 1, m = tid & 1;
        float acc = hb3[m];
        for (int k = 0; k < 64; ++k) acc += y2[(bb << 6) + k] * hW3[k * 2 + m];
        float sp = fmaxf(acc, 0.f) + log1pf(expf(-fabsf(acc)));
        out[tid] = sp + 1e-6f;
    }
}

// ---------------------------------------------------------------------------
extern "C" void kernel_launch(void* const* d_in, const int* in_sizes, int n_in,
                              void* d_out, int out_size, void* d_ws, size_t ws_size,
                              hipStream_t stream) {
    const float* snap  = (const float*)d_in[0];
    const int*   edges = (const int*)d_in[1];
    const float* scale = (const float*)d_in[2];
    const float* shift = (const float*)d_in[3];
    const float* W1 = (const float*)d_in[4];
    const float* b1 = (const float*)d_in[5];
    const float* W2 = (const float*)d_in[6];
    const float* b2 = (const float*)d_in[7];
    const float* W3 = (const float*)d_in[8];
    const float* b3 = (const float*)d_in[9];
    const float* Wih0 = (const float*)d_in[10];
    const float* Whh0 = (const float*)d_in[11];
    const float* bih0 = (const float*)d_in[12];
    const float* bhh0 = (const float*)d_in[13];
    const float* Wih1 = (const float*)d_in[14];
    const float* Whh1 = (const float*)d_in[15];
    const float* bih1 = (const float*)d_in[16];
    const float* bhh1 = (const float*)d_in[17];
    const float* hW1 = (const float*)d_in[18];
    const float* hb1 = (const float*)d_in[19];
    const float* hW2 = (const float*)d_in[20];
    const float* hb2 = (const float*)d_in[21];
    const float* hW3 = (const float*)d_in[22];
    const float* hb3 = (const float*)d_in[23];

    // workspace carve (float indices); ~7.2 MB
    float* ws = (float*)d_ws;
    float* bias0 = ws + 0;                        // 512
    float* bias1 = ws + 512;                      // 512
    unsigned short* AbG  = (unsigned short*)(ws + 1024);   // 8192 f
    unsigned short* Wt2g = (unsigned short*)(ws + 9216);   // 8192 f
    unsigned short* Wt3g = (unsigned short*)(ws + 17408);  // 8192 f
    float* WT0 = ws + 25600;                      // 65536
    float* WT1 = ws + 91136;                      // 65536
    unsigned int* Wc0 = (unsigned int*)(ws + 156672);      // 32768
    unsigned int* Wc1 = (unsigned int*)(ws + 189440);      // 32768
    float* emb   = ws + 222208;                   // 262144
    float* inp   = ws + 484352;                   // 1048576 (both LSTM layers)
    float* h0seq = ws + 1532928;                  // 262144
    float* hfin  = ws + 1795072;                  // 1024

    const int smem_gcn = 73104;   // 2 blocks/CU (was 142736 -> 1 block/CU)
    hipFuncSetAttribute((const void*)gcn_kernel,
                        hipFuncAttributeMaxDynamicSharedMemorySize, smem_gcn);

    prep_kernel<<<1, 256, 0, stream>>>(edges, bih0, bhh0, bih1, bhh1,
                                       bias0, bias1, AbG);
    convw_kernel<<<32, 512, 0, stream>>>(W2, Wt2g);
    convw_kernel<<<32, 512, 0, stream>>>(W3, Wt3g);
    convh_kernel<<<64, 512, 0, stream>>>(Whh0, Wc0);
    convh_kernel<<<64, 512, 0, stream>>>(Whh1, Wc1);
    transpose_kernel<<<128, 512, 0, stream>>>(Wih0, WT0);
    transpose_kernel<<<128, 512, 0, stream>>>(Wih1, WT1);
    gcn_kernel<<<GG, 512, smem_gcn, stream>>>(snap, scale, shift, W1, b1, b2, b3,
                                              AbG, Wt2g, Wt3g, emb);
    proj_kernel<<<GG, 512, 0, stream>>>(emb, WT0, bias0, inp);
    scan_kernel<<<BB, 512, 0, stream>>>(inp, Wc0, h0seq, 1);
    proj_kernel<<<GG, 512, 0, stream>>>(h0seq, WT1, bias1, inp);
    scan_kernel<<<BB, 512, 0, stream>>>(inp, Wc1, hfin, 0);
    head_kernel<<<1, 256, 0, stream>>>(hfin, hW1, hb1, hW2, hb2, hW3, hb3, (float*)d_out);
}

// Round 14
// 604.017 us; speedup vs baseline: 1.0812x; 1.0382x over previous
//
#include <hip/hip_runtime.h>
#include <math.h>

// Problem constants
#define NN 118   // nodes
#define EE 372   // edges
#define GG 2048  // B*T
#define DD 128   // hidden
#define TT 256   // seq len
#define BB 8     // batch
#define FD 512   // 4*D

// LDS strides (bf16 elems; rows 16B-aligned)
#define XS 136   // xb2 row stride (128 cols + pad)
#define MS 264   // hS2 row stride (256 cols + pad)

typedef short bf16x8 __attribute__((ext_vector_type(8)));
typedef float f32x4  __attribute__((ext_vector_type(4)));
typedef _Float16 f16x2 __attribute__((ext_vector_type(2)));

__device__ __forceinline__ float frcp_(float x) { return __builtin_amdgcn_rcpf(x); }
__device__ __forceinline__ float sig_f(float x) { return frcp_(1.0f + __expf(-x)); }
__device__ __forceinline__ float tanh_f(float x) { return 1.0f - 2.0f * frcp_(__expf(2.0f * x) + 1.0f); }
__device__ __forceinline__ float silu_f(float x) { return x * frcp_(1.0f + __expf(-x)); }
__device__ __forceinline__ float siluf_(float x) { return x / (1.0f + expf(-x)); }

// f16-pair dot with fp32 accumulate (v_dot2_f32_f16); scalar fallback.
__device__ __forceinline__ float fdot2_(unsigned int a, unsigned int b, float c) {
#if defined(__has_builtin) && __has_builtin(__builtin_amdgcn_fdot2)
    return __builtin_amdgcn_fdot2(__builtin_bit_cast(f16x2, a),
                                  __builtin_bit_cast(f16x2, b), c, false);
#else
    f16x2 x = __builtin_bit_cast(f16x2, a), y = __builtin_bit_cast(f16x2, b);
    return c + (float)x[0] * (float)y[0] + (float)x[1] * (float)y[1];
#endif
}

// Barrier draining only LDS ops (lgkmcnt), not vmcnt.
__device__ __forceinline__ void bar_lds() {
    asm volatile("s_waitcnt lgkmcnt(0)\n\ts_barrier" ::: "memory");
}

__device__ __forceinline__ unsigned short f2bf(float x) {
    unsigned int u = __float_as_uint(x);
    unsigned int r = (u + 0x7fffu + ((u >> 16) & 1u)) >> 16;
    return (unsigned short)r;
}
__device__ __forceinline__ float bf2f(unsigned short b) {
    return __uint_as_float(((unsigned int)b) << 16);
}

// ---------------------------------------------------------------------------
// prep: dense normalized adjacency A -> bf16 128x128 (zero padded), fused
// LSTM biases. 1 block.
// ---------------------------------------------------------------------------
__global__ void prep_kernel(const int* __restrict__ ei,
                            const float* __restrict__ bih0, const float* __restrict__ bhh0,
                            const float* __restrict__ bih1, const float* __restrict__ bhh1,
                            float* __restrict__ bias0, float* __restrict__ bias1,
                            unsigned short* __restrict__ AbG) {
    __shared__ int sflag;
    __shared__ int ssrc[EE], sdst[EE];
    __shared__ int scount[NN];
    __shared__ float sinv[NN];
    __shared__ float Adense[NN * NN];  // 55.7 KB
    int tid = threadIdx.x;
    if (tid == 0) sflag = 0;
    __syncthreads();
    for (int i = tid; i < 2 * EE; i += blockDim.x)
        if ((i & 1) && ei[i] != 0) atomicOr(&sflag, 1);
    __syncthreads();
    bool m64 = (sflag == 0);
    for (int e = tid; e < EE; e += blockDim.x) {
        int s, d;
        if (m64) { s = ei[2 * e]; d = ei[2 * EE + 2 * e]; }
        else     { s = ei[e];     d = ei[EE + e]; }
        s = min(max(s, 0), NN - 1); d = min(max(d, 0), NN - 1);
        ssrc[e] = s; sdst[e] = d;
    }
    for (int n = tid; n < NN; n += blockDim.x) scount[n] = 0;
    for (int i = tid; i < NN * NN; i += blockDim.x) Adense[i] = 0.0f;
    __syncthreads();
    for (int e = tid; e < EE; e += blockDim.x) atomicAdd(&scount[sdst[e]], 1);
    __syncthreads();
    for (int n = tid; n < NN; n += blockDim.x) {
        float deg = 1.0f + (float)scount[n];
        sinv[n] = rsqrtf(deg);
        Adense[n * NN + n] = 1.0f / deg;   // self term h*(1/deg)
    }
    __syncthreads();
    for (int e = tid; e < EE; e += blockDim.x)
        atomicAdd(&Adense[sdst[e] * NN + ssrc[e]], sinv[ssrc[e]] * sinv[sdst[e]]);
    __syncthreads();
    for (int i = tid; i < 128 * 128; i += blockDim.x) {
        int r = i >> 7, c = i & 127;
        AbG[i] = (r < NN && c < NN) ? f2bf(Adense[r * NN + c]) : (unsigned short)0;
    }
    for (int j = tid; j < FD; j += blockDim.x) {
        bias0[j] = bih0[j] + bhh0[j];
        bias1[j] = bih1[j] + bhh1[j];
    }
}

// ---------------------------------------------------------------------------
// W (K=128 x N=128, fp32) -> bf16 [n][k] for MFMA B-frags
// ---------------------------------------------------------------------------
__global__ void convw_kernel(const float* __restrict__ W, unsigned short* __restrict__ out) {
    int i = blockIdx.x * 512 + threadIdx.x;  // 16384 total
    int n = i >> 7, k = i & 127;
    out[i] = f2bf(W[k * DD + n]);
}

// ---------------------------------------------------------------------------
// Whh -> f16 pairs for the K-split-4 scan (round-11 layout)
// ---------------------------------------------------------------------------
__global__ void convh_kernel(const float* __restrict__ W, unsigned int* __restrict__ out) {
    int i = blockIdx.x * 512 + threadIdx.x;  // 32768 total
    int d = i & 127;
    int rest = i >> 7;
    int quarter = rest & 3;
    int qg = rest >> 2;
    int q = qg & 15, g = qg >> 4;
    const float* row = W + (size_t)(g * 128 + d) * 128 + quarter * 32;
    float a = row[2 * q], b = row[2 * q + 1];
    unsigned short lo = __builtin_bit_cast(unsigned short, (_Float16)a);
    unsigned short hi = __builtin_bit_cast(unsigned short, (_Float16)b);
    out[i] = (unsigned int)lo | ((unsigned int)hi << 16);
}

// ---------------------------------------------------------------------------
// Wih (512x128) -> WT [k=128][j=512] so proj reads coalesced
// ---------------------------------------------------------------------------
__global__ void transpose_kernel(const float* __restrict__ in, float* __restrict__ out) {
    int idx = blockIdx.x * blockDim.x + threadIdx.x;  // 65536 total
    int j = idx >> 7, k = idx & 127;
    out[k * FD + j] = in[idx];
}

// ---------------------------------------------------------------------------
// GCN, TWO GRAPHS PER BLOCK (round 14): waves 0-3 serve graph 0, waves 4-7
// graph 1. A (adjacency) and W (weights) are graph-invariant -> per-wave
// operand loads unchanged while MFMA per phase doubles (64/wave: 4m x 4n
// tiles of 16), barriers per graph halve. A/W read from global (L2/L1-hot).
// LDS: xb2 [256][XS] bf16 + hS2 [128][MS] bf16 = 137KB -> 1 block/CU.
// ---------------------------------------------------------------------------
// mm_agg: xb2[gr*128+m][n] = silu(AbG[m][k] @ hS2[n][gr*128+k] + bias[n])
__device__ __forceinline__ void mm_agg2(const unsigned short* __restrict__ AbG,
                                        const unsigned short* __restrict__ hS2,
                                        unsigned short* __restrict__ xb2,
                                        const float* __restrict__ bias,
                                        int gr, int wm, int wn, int lm, int lq) {
    f32x4 acc[4][4];
#pragma unroll
    for (int mt = 0; mt < 4; ++mt)
#pragma unroll
        for (int nt = 0; nt < 4; ++nt) acc[mt][nt] = (f32x4){0.f, 0.f, 0.f, 0.f};
#pragma unroll
    for (int kb = 0; kb < 4; ++kb) {
        int ko = kb * 32 + lq * 8;
        bf16x8 bfr[4];
#pragma unroll
        for (int nt = 0; nt < 4; ++nt)
            bfr[nt] = *(const bf16x8*)(hS2 + (wn + nt * 16 + lm) * MS + gr * 128 + ko);
#pragma unroll
        for (int mt = 0; mt < 4; ++mt) {
            bf16x8 af = *(const bf16x8*)(AbG + (wm + mt * 16 + lm) * 128 + ko);  // global, hot
#pragma unroll
            for (int nt = 0; nt < 4; ++nt)
                acc[mt][nt] = __builtin_amdgcn_mfma_f32_16x16x32_bf16(af, bfr[nt], acc[mt][nt], 0, 0, 0);
        }
    }
#pragma unroll
    for (int nt = 0; nt < 4; ++nt) {
        float bn = bias[wn + nt * 16 + lm];
        int col = wn + nt * 16 + lm;
#pragma unroll
        for (int mt = 0; mt < 4; ++mt)
#pragma unroll
            for (int i = 0; i < 4; ++i) {
                float v = silu_f(acc[mt][nt][i] + bn);
                xb2[(gr * 128 + wm + mt * 16 + lq * 4 + i) * XS + col] = f2bf(v);
            }
    }
}

// mm_xw: hS2[n=dout][gr*128+m] = xb2[gr*128+m][k] @ WtG[n][k]  (bf16 out)
__device__ __forceinline__ void mm_xw2(const unsigned short* __restrict__ xb2,
                                       const unsigned short* __restrict__ WtG,
                                       unsigned short* __restrict__ hS2,
                                       int gr, int wm, int wn, int lm, int lq) {
    f32x4 acc[4][4];
#pragma unroll
    for (int mt = 0; mt < 4; ++mt)
#pragma unroll
        for (int nt = 0; nt < 4; ++nt) acc[mt][nt] = (f32x4){0.f, 0.f, 0.f, 0.f};
#pragma unroll
    for (int kb = 0; kb < 4; ++kb) {
        int ko = kb * 32 + lq * 8;
        bf16x8 bfr[4];
#pragma unroll
        for (int nt = 0; nt < 4; ++nt)
            bfr[nt] = *(const bf16x8*)(WtG + (wn + nt * 16 + lm) * 128 + ko);  // global, hot
#pragma unroll
        for (int mt = 0; mt < 4; ++mt) {
            bf16x8 af = *(const bf16x8*)(xb2 + (gr * 128 + wm + mt * 16 + lm) * XS + ko);
#pragma unroll
            for (int nt = 0; nt < 4; ++nt)
                acc[mt][nt] = __builtin_amdgcn_mfma_f32_16x16x32_bf16(af, bfr[nt], acc[mt][nt], 0, 0, 0);
        }
    }
#pragma unroll
    for (int nt = 0; nt < 4; ++nt)
#pragma unroll
        for (int mt = 0; mt < 4; ++mt) {
            f32x4 a = acc[mt][nt];
            ushort4 pk;
            pk.x = f2bf(a[0]); pk.y = f2bf(a[1]); pk.z = f2bf(a[2]); pk.w = f2bf(a[3]);
            *(ushort4*)(hS2 + (wn + nt * 16 + lm) * MS + gr * 128 + wm + mt * 16 + lq * 4) = pk;
        }
}

__global__ __launch_bounds__(512, 2) void gcn_kernel(
    const float* __restrict__ xg, const float* __restrict__ scale, const float* __restrict__ shift,
    const float* __restrict__ W1, const float* __restrict__ b1,
    const float* __restrict__ b2, const float* __restrict__ b3,
    const unsigned short* __restrict__ AbG,
    const unsigned short* __restrict__ Wt2g, const unsigned short* __restrict__ Wt3g,
    float* __restrict__ emb) {
    extern __shared__ char smem[];
    unsigned short* xb2 = (unsigned short*)smem;             // 256*136*2 = 69632 B
    unsigned short* hS2 = (unsigned short*)(smem + 69632);   // 128*264*2 = 67584 B
    float* xin2  = (float*)(smem + 137216);                  // 2*354 f = 2832 B
    float* meanS = (float*)(smem + 140048);                  // 512 f = 2048 B (end 142096)
    int tid = threadIdx.x;
    int lane = tid & 63, w = tid >> 6;
    int gr = w >> 2;            // graph within block (0/1)
    int wl = w & 3;             // wave within graph
    int lm = lane & 15, lq = lane >> 4;
    int wm = (wl & 1) * 64, wn = (wl >> 1) * 64;
    int g0 = blockIdx.x * 2;

    // zero hS2 fully (pad-col safety) + xb2 pad rows of both graphs
    for (int i = tid; i < 4224; i += 512) ((uint4*)hS2)[i] = (uint4){0, 0, 0, 0};
    for (int i = tid; i < 2 * 10 * 64; i += 512) {
        int grr = i >= 640;
        int ii = i - grr * 640;
        int r = grr * 128 + NN + (ii >> 6), c = (ii & 63) * 2;
        *(unsigned int*)(xb2 + r * XS + c) = 0u;
    }
    // stage inputs (scale/shift) for both graphs
    float s0 = scale[0], s1 = scale[1], s2 = scale[2];
    float t0 = shift[0], t1 = shift[1], t2 = shift[2];
    for (int i = tid; i < 2 * NN * 3; i += 512) {
        int gi = (i >= NN * 3) ? 1 : 0;
        int idx = i - gi * (NN * 3);
        int f = idx % 3;
        float sc = (f == 0) ? s0 : ((f == 1) ? s1 : s2);
        float sf = (f == 0) ? t0 : ((f == 1) ? t1 : t2);
        xin2[gi * 354 + idx] = xg[(size_t)(g0 + gi) * (NN * 3) + idx] * sc + sf;
    }
    // per-lane constants: bias values live in global (small, L1-hot) -- pass ptr
    int dd = lane * 2;
    float2 w10 = *(const float2*)(W1 + dd);
    float2 w11 = *(const float2*)(W1 + DD + dd);
    float2 w12 = *(const float2*)(W1 + 2 * DD + dd);
    bar_lds();
    // layer 1 (K=3): wave-per-node within each graph's 4 waves
    const float* xin = xin2 + gr * 354;
    for (int k = 0; k < 30; ++k) {
        int n = wl + 4 * k;
        if (n >= NN) break;  // wave-uniform within graph
        float x0 = xin[n * 3], x1 = xin[n * 3 + 1], x2 = xin[n * 3 + 2];
        hS2[dd * MS + gr * 128 + n]       = f2bf(x0 * w10.x + x1 * w11.x + x2 * w12.x);
        hS2[(dd + 1) * MS + gr * 128 + n] = f2bf(x0 * w10.y + x1 * w11.y + x2 * w12.y);
    }
    bar_lds();
    mm_agg2(AbG, hS2, xb2, b1, gr, wm, wn, lm, lq);   // x1
    bar_lds();
    mm_xw2(xb2, Wt2g, hS2, gr, wm, wn, lm, lq);       // h2
    bar_lds();
    mm_agg2(AbG, hS2, xb2, b2, gr, wm, wn, lm, lq);   // x2
    bar_lds();
    mm_xw2(xb2, Wt3g, hS2, gr, wm, wn, lm, lq);       // h3
    bar_lds();
    mm_agg2(AbG, hS2, xb2, b3, gr, wm, wn, lm, lq);   // x3
    bar_lds();
    // mean over nodes, per graph (118 = 2 x 59)
    {
        int grr = tid >> 8, t2 = tid & 255;
        int part = t2 >> 7, d = t2 & 127;
        int a0 = part * 59, a1 = a0 + 59;
        float s = 0.f;
        for (int n = a0; n < a1; ++n) s += bf2f(xb2[(grr * 128 + n) * XS + d]);
        meanS[grr * 256 + part * 128 + d] = s;
    }
    bar_lds();
    if (tid < 256) {
        int grr = tid >> 7, d = tid & 127;
        float s = meanS[grr * 256 + d] + meanS[grr * 256 + 128 + d];
        emb[(size_t)(g0 + grr) * DD + d] = s * (1.0f / (float)NN);
    }
}

// ---------------------------------------------------------------------------
// proj: dst[g][j] = bias[j] + sum_k src[g][k] * WT[k][j]
// ---------------------------------------------------------------------------
__global__ __launch_bounds__(512) void proj_kernel(const float* __restrict__ src,
                                                   const float* __restrict__ WT,
                                                   const float* __restrict__ bias,
                                                   float* __restrict__ dst) {
    __shared__ __align__(16) float eL[DD];
    int g = blockIdx.x, tid = threadIdx.x;
    if (tid < DD) eL[tid] = src[(size_t)g * DD + tid];
    __syncthreads();
    float acc = bias[tid];
    const float* wt = WT + tid;
#pragma unroll 8
    for (int k = 0; k < DD; ++k) acc += eL[k] * wt[(size_t)k * FD];
    dst[(size_t)g * FD + tid] = acc;
}

// ---------------------------------------------------------------------------
// LSTM scan (round-11 config, the scan plateau winner: 147 us/layer).
// ---------------------------------------------------------------------------
__global__ __launch_bounds__(512, 2) void scan_kernel(
    const float* __restrict__ inp,
    const unsigned int* __restrict__ Wc,
    float* __restrict__ hout, int full) {
    __shared__ __align__(16) unsigned short hL[DD];
    __shared__ __align__(16) float sgP[3 * DD * 4];
    int b = blockIdx.x, j = threadIdx.x;
    int d = j & 127, quarter = j >> 7;
    unsigned int wreg[4][16];
#pragma unroll
    for (int g = 0; g < 4; ++g)
#pragma unroll
        for (int q = 0; q < 16; ++q)
            wreg[g][q] = Wc[(((g * 16 + q) << 2) + quarter) * 128 + d];
#pragma unroll
    for (int g = 0; g < 4; ++g)
#pragma unroll
        for (int q = 0; q < 16; ++q)
            asm volatile("" : "+v"(wreg[g][q]));
    if (j < 64) ((unsigned int*)hL)[j] = 0u;
    float creg = 0.f;
    const float* ib = inp + (size_t)b * TT * FD;
    float* hb_ = hout + (size_t)b * (full ? TT * DD : DD);
    float xg0[4], xg1[4];
    if (quarter == 0) {
#pragma unroll
        for (int g = 0; g < 4; ++g) { xg0[g] = ib[g * DD + d]; xg1[g] = ib[FD + g * DD + d]; }
    }
    bar_lds();
    for (int t = 0; t < TT; ++t) {
        float xg2[4];
        if (quarter == 0) {
            bool more = (t + 2 < TT);
#pragma unroll
            for (int g = 0; g < 4; ++g)
                xg2[g] = more ? ib[(t + 2) * FD + g * DD + d] : 0.f;
        }
        const uint4* h4 = (const uint4*)(hL + quarter * 32);
        float a0 = 0.f, a1 = 0.f, a2 = 0.f, a3 = 0.f;
#pragma unroll
        for (int c = 0; c < 4; ++c) {
            uint4 hv = h4[c];
            a0 = fdot2_(wreg[0][4 * c + 0], hv.x, a0);
            a1 = fdot2_(wreg[1][4 * c + 0], hv.x, a1);
            a2 = fdot2_(wreg[2][4 * c + 0], hv.x, a2);
            a3 = fdot2_(wreg[3][4 * c + 0], hv.x, a3);
            a0 = fdot2_(wreg[0][4 * c + 1], hv.y, a0);
            a1 = fdot2_(wreg[1][4 * c + 1], hv.y, a1);
            a2 = fdot2_(wreg[2][4 * c + 1], hv.y, a2);
            a3 = fdot2_(wreg[3][4 * c + 1], hv.y, a3);
            a0 = fdot2_(wreg[0][4 * c + 2], hv.z, a0);
            a1 = fdot2_(wreg[1][4 * c + 2], hv.z, a1);
            a2 = fdot2_(wreg[2][4 * c + 2], hv.z, a2);
            a3 = fdot2_(wreg[3][4 * c + 2], hv.z, a3);
            a0 = fdot2_(wreg[0][4 * c + 3], hv.w, a0);
            a1 = fdot2_(wreg[1][4 * c + 3], hv.w, a1);
            a2 = fdot2_(wreg[2][4 * c + 3], hv.w, a2);
            a3 = fdot2_(wreg[3][4 * c + 3], hv.w, a3);
        }
        if (quarter != 0)
            *(float4*)(sgP + ((quarter - 1) * DD + d) * 4) = make_float4(a0, a1, a2, a3);
        bar_lds();
        if (quarter == 0) {
            float4 p1 = *(const float4*)(sgP + d * 4);
            float4 p2 = *(const float4*)(sgP + (DD + d) * 4);
            float4 p3 = *(const float4*)(sgP + (2 * DD + d) * 4);
            float iv = sig_f(a0 + p1.x + p2.x + p3.x + xg0[0]);
            float fv = sig_f(a1 + p1.y + p2.y + p3.y + xg0[1]);
            float gv = tanh_f(a2 + p1.z + p2.z + p3.z + xg0[2]);
            float ov = sig_f(a3 + p1.w + p2.w + p3.w + xg0[3]);
            float cn = fv * creg + iv * gv;
            creg = cn;
            float hn = ov * tanh_f(cn);
            ((_Float16*)hL)[d] = (_Float16)hn;
            if (full) hb_[t * DD + d] = hn;
            else if (t == TT - 1) hb_[d] = hn;
#pragma unroll
            for (int g = 0; g < 4; ++g) { xg0[g] = xg1[g]; xg1[g] = xg2[g]; }
        }
        bar_lds();
    }
}

// ---------------------------------------------------------------------------
// head MLP on final hidden state. 1 block.
// ---------------------------------------------------------------------------
__global__ void head_kernel(const float* __restrict__ hfin,
                            const float* __restrict__ hW1, const float* __restrict__ hb1,
                            const float* __restrict__ hW2, const float* __restrict__ hb2,
                            const float* __restrict__ hW3, const float* __restrict__ hb3,
                            float* __restrict__ out) {
    __shared__ float fh[BB * DD];
    __shared__ float y1[BB * DD];
    __shared__ float y2[BB * 64];
    int tid = threadIdx.x;
    for (int i = tid; i < BB * DD; i += 256) fh[i] = hfin[i];
    __syncthreads();
    for (int i = tid; i < BB * DD; i += 256) {
        int bb = i >> 7, jj = i & 127;
        float acc = hb1[jj];
        for (int k = 0; k < DD; ++k) acc += fh[(bb << 7) + k] * hW1[(k << 7) + jj];
        y1[i] = siluf_(acc);
    }
    __syncthreads();
    for (int i = tid; i < BB * 64; i += 256) {
        int bb = i >> 6, jj = i & 63;
        float acc = hb2[jj];
        for (int k = 0; k < DD; ++k) acc += y1[(bb << 7) + k] * hW2[(k << 6) + jj];
        y2[i] = siluf_(acc);
    }
    __syncthreads();
    if (tid < BB * 2) {
        int bb = tid >> 1, m = tid & 1;
        float acc = hb3[m];
        for (int k = 0; k < 64; ++k) acc += y2[(bb << 6) + k] * hW3[k * 2 + m];
        float sp = fmaxf(acc, 0.f) + log1pf(expf(-fabsf(acc)));
        out[tid] = sp + 1e-6f;
    }
}

// ---------------------------------------------------------------------------
extern "C" void kernel_launch(void* const* d_in, const int* in_sizes, int n_in,
                              void* d_out, int out_size, void* d_ws, size_t ws_size,
                              hipStream_t stream) {
    const float* snap  = (const float*)d_in[0];
    const int*   edges = (const int*)d_in[1];
    const float* scale = (const float*)d_in[2];
    const float* shift = (const float*)d_in[3];
    const float* W1 = (const float*)d_in[4];
    const float* b1 = (const float*)d_in[5];
    const float* W2 = (const float*)d_in[6];
    const float* b2 = (const float*)d_in[7];
    const float* W3 = (const float*)d_in[8];
    const float* b3 = (const float*)d_in[9];
    const float* Wih0 = (const float*)d_in[10];
    const float* Whh0 = (const float*)d_in[11];
    const float* bih0 = (const float*)d_in[12];
    const float* bhh0 = (const float*)d_in[13];
    const float* Wih1 = (const float*)d_in[14];
    const float* Whh1 = (const float*)d_in[15];
    const float* bih1 = (const float*)d_in[16];
    const float* bhh1 = (const float*)d_in[17];
    const float* hW1 = (const float*)d_in[18];
    const float* hb1 = (const float*)d_in[19];
    const float* hW2 = (const float*)d_in[20];
    const float* hb2 = (const float*)d_in[21];
    const float* hW3 = (const float*)d_in[22];
    const float* hb3 = (const float*)d_in[23];

    // workspace carve (float indices); ~7.2 MB
    float* ws = (float*)d_ws;
    float* bias0 = ws + 0;                        // 512
    float* bias1 = ws + 512;                      // 512
    unsigned short* AbG  = (unsigned short*)(ws + 1024);   // 8192 f
    unsigned short* Wt2g = (unsigned short*)(ws + 9216);   // 8192 f
    unsigned short* Wt3g = (unsigned short*)(ws + 17408);  // 8192 f
    float* WT0 = ws + 25600;                      // 65536
    float* WT1 = ws + 91136;                      // 65536
    unsigned int* Wc0 = (unsigned int*)(ws + 156672);      // 32768
    unsigned int* Wc1 = (unsigned int*)(ws + 189440);      // 32768
    float* emb   = ws + 222208;                   // 262144
    float* inp   = ws + 484352;                   // 1048576 (both LSTM layers)
    float* h0seq = ws + 1532928;                  // 262144
    float* hfin  = ws + 1795072;                  // 1024

    const int smem_gcn = 142096;
    hipFuncSetAttribute((const void*)gcn_kernel,
                        hipFuncAttributeMaxDynamicSharedMemorySize, smem_gcn);

    prep_kernel<<<1, 256, 0, stream>>>(edges, bih0, bhh0, bih1, bhh1,
                                       bias0, bias1, AbG);
    convw_kernel<<<32, 512, 0, stream>>>(W2, Wt2g);
    convw_kernel<<<32, 512, 0, stream>>>(W3, Wt3g);
    convh_kernel<<<64, 512, 0, stream>>>(Whh0, Wc0);
    convh_kernel<<<64, 512, 0, stream>>>(Whh1, Wc1);
    transpose_kernel<<<128, 512, 0, stream>>>(Wih0, WT0);
    transpose_kernel<<<128, 512, 0, stream>>>(Wih1, WT1);
    gcn_kernel<<<GG / 2, 512, smem_gcn, stream>>>(snap, scale, shift, W1, b1, b2, b3,
                                                  AbG, Wt2g, Wt3g, emb);
    proj_kernel<<<GG, 512, 0, stream>>>(emb, WT0, bias0, inp);
    scan_kernel<<<BB, 512, 0, stream>>>(inp, Wc0, h0seq, 1);
    proj_kernel<<<GG, 512, 0, stream>>>(h0seq, WT1, bias1, inp);
    scan_kernel<<<BB, 512, 0, stream>>>(inp, Wc1, hfin, 0);
    head_kernel<<<1, 256, 0, stream>>>(hfin, hW1, hb1, hW2, hb2, hW3, hb3, (float*)d_out);
}